// Round 8
// baseline (398.282 us; speedup 1.0000x reference)
//
#include <hip/hip_runtime.h>
#include <hip/hip_bf16.h>

// out[i,f] = a[f]*x[i,f] + b[f], a/b per group of 32 features.
// x: [2097152, 128] fp32 = 1 GiB in + 1 GiB out -> pure HBM-streaming.
// Round 8: R7's one-shot exact-fit ordered sweep, burst depth 4 -> 8.
// Each block = ONE contiguous 32 KiB chunk; each wave issues 8 adjacent
// 1 KiB load bursts fully in flight before any store waits on vmcnt.
// History: R1 simple loop 443; R2 nt 485; R3 strided unroll 468;
// R4 adjacent-chunk loop 396; R5 block-contiguous 409; R6 sw-pipeline 407;
// R7 one-shot 16KiB chunks 383.6 (5.60 TB/s, 89% of copy ceiling).

typedef float f4 __attribute__((ext_vector_type(4)));

#define BLOCK 256
#define DEPTH 8
#define CHUNK ((long long)DEPTH * BLOCK)   // 2048 f4 = 32 KiB per block

__global__ __launch_bounds__(BLOCK) void normalize_kernel(
    const f4* __restrict__ x,
    const float* __restrict__ x_min,
    const float* __restrict__ x_max,
    const float* __restrict__ u,
    const float* __restrict__ l,
    f4* __restrict__ out,
    long long n4)
{
    const int tid = threadIdx.x;
    const long long i = (long long)blockIdx.x * CHUNK + tid;

    // chunk base is a multiple of 2048 -> (idx & 31) == (tid & 31):
    // group invariant per thread.
    const int g = (tid & 31) >> 3;
    const float s = (u[g] - l[g]) / (x_max[g] - x_min[g]);
    const float b = l[g] - x_min[g] * s;

    if (i + (DEPTH - 1) * BLOCK < n4) {
        // Full chunk (the only path for the bench shape).
        f4 v[DEPTH];
        #pragma unroll
        for (int k = 0; k < DEPTH; ++k) v[k] = x[i + k * BLOCK];
        f4 o[DEPTH];
        #pragma unroll
        for (int k = 0; k < DEPTH; ++k) {
            #pragma unroll
            for (int j = 0; j < 4; ++j) o[k][j] = fmaf(s, v[k][j], b);
        }
        #pragma unroll
        for (int k = 0; k < DEPTH; ++k) out[i + k * BLOCK] = o[k];
    } else {
        // Partial chunk tail (not taken for the bench shape).
        for (long long j = i; j < n4; j += BLOCK) {
            f4 v = x[j];
            f4 o;
            #pragma unroll
            for (int k = 0; k < 4; ++k) o[k] = fmaf(s, v[k], b);
            out[j] = o;
        }
    }
}

extern "C" void kernel_launch(void* const* d_in, const int* in_sizes, int n_in,
                              void* d_out, int out_size, void* d_ws, size_t ws_size,
                              hipStream_t stream) {
    const f4*    x     = (const f4*)d_in[0];
    const float* x_min = (const float*)d_in[1];
    const float* x_max = (const float*)d_in[2];
    const float* u     = (const float*)d_in[3];
    const float* l     = (const float*)d_in[4];
    f4* out = (f4*)d_out;

    const long long n4 = (long long)out_size / 4;

    // Exact-fit: one 32 KiB chunk per block, dispatched in address order.
    long long grid = (n4 + CHUNK - 1) / CHUNK;   // 32768 for the bench shape
    if (grid < 1) grid = 1;

    normalize_kernel<<<(int)grid, BLOCK, 0, stream>>>(x, x_min, x_max, u, l,
                                                      out, n4);
}

// Round 9
// 381.954 us; speedup vs baseline: 1.0427x; 1.0427x over previous
//
#include <hip/hip_runtime.h>
#include <hip/hip_bf16.h>

// out[i,f] = a[f]*x[i,f] + b[f], a/b per group of 32 features.
// x: [2097152, 128] fp32 = 1 GiB in + 1 GiB out -> pure HBM-streaming.
// FINAL (= Round 7 best, 383.6 us = 5.60 TB/s, 89% of the 6.29 TB/s
// float4-copy ceiling): one-shot exact-fit grid. Each block = exactly ONE
// contiguous 16 KiB chunk, no grid-stride loop: 65536 blocks dispatched in
// address order -> perfectly ordered chip-wide sweep, wave churn sustains
// in-flight depth, zero loop overhead.
// Ladder: R1 simple loop 443; R2 nontemporal 485 (X); R3 strided unroll
// 468 (X); R4 adjacent 16KiB chunks 396; R5 block-contiguous 409 (X);
// R6 sw-pipeline 407 (X); R7 one-shot 383.6 (BEST); R8 depth-8 398 (X).
// Levers that mattered: burst adjacency (R4), one-shot ordered sweep (R7).

typedef float f4 __attribute__((ext_vector_type(4)));

#define BLOCK 256
#define CHUNK (4LL * BLOCK)   // 1024 f4 = 16 KiB per block

__global__ __launch_bounds__(BLOCK) void normalize_kernel(
    const f4* __restrict__ x,
    const float* __restrict__ x_min,
    const float* __restrict__ x_max,
    const float* __restrict__ u,
    const float* __restrict__ l,
    f4* __restrict__ out,
    long long n4)
{
    const int tid = threadIdx.x;
    const long long i = (long long)blockIdx.x * CHUNK + tid;

    // chunk base is a multiple of 1024 -> (idx & 31) == (tid & 31):
    // group invariant per thread.
    const int g = (tid & 31) >> 3;
    const float s = (u[g] - l[g]) / (x_max[g] - x_min[g]);
    const float b = l[g] - x_min[g] * s;

    if (i + 3 * BLOCK < n4) {
        // Full chunk (the only path for the bench shape).
        f4 v0 = x[i];
        f4 v1 = x[i + 1 * BLOCK];
        f4 v2 = x[i + 2 * BLOCK];
        f4 v3 = x[i + 3 * BLOCK];
        f4 o0, o1, o2, o3;
        #pragma unroll
        for (int k = 0; k < 4; ++k) {
            o0[k] = fmaf(s, v0[k], b);
            o1[k] = fmaf(s, v1[k], b);
            o2[k] = fmaf(s, v2[k], b);
            o3[k] = fmaf(s, v3[k], b);
        }
        out[i]             = o0;
        out[i + 1 * BLOCK] = o1;
        out[i + 2 * BLOCK] = o2;
        out[i + 3 * BLOCK] = o3;
    } else {
        // Partial chunk tail (not taken for the bench shape).
        for (long long j = i; j < n4; j += BLOCK) {
            f4 v = x[j];
            f4 o;
            #pragma unroll
            for (int k = 0; k < 4; ++k) o[k] = fmaf(s, v[k], b);
            out[j] = o;
        }
    }
}

extern "C" void kernel_launch(void* const* d_in, const int* in_sizes, int n_in,
                              void* d_out, int out_size, void* d_ws, size_t ws_size,
                              hipStream_t stream) {
    const f4*    x     = (const f4*)d_in[0];
    const float* x_min = (const float*)d_in[1];
    const float* x_max = (const float*)d_in[2];
    const float* u     = (const float*)d_in[3];
    const float* l     = (const float*)d_in[4];
    f4* out = (f4*)d_out;

    const long long n4 = (long long)out_size / 4;

    // Exact-fit: one 16 KiB chunk per block, dispatched in address order.
    long long grid = (n4 + CHUNK - 1) / CHUNK;   // 65536 for the bench shape
    if (grid < 1) grid = 1;

    normalize_kernel<<<(int)grid, BLOCK, 0, stream>>>(x, x_min, x_max, u, l,
                                                      out, n4);
}